// Round 1
// baseline (712.019 us; speedup 1.0000x reference)
//
#include <hip/hip_runtime.h>
#include <cmath>

// ---------------------------------------------------------------------------
// HyperbolicScaleHead: trunk MLP -> (degenerate seqlen-1 attention == v-proj)
// -> LN -> FFN -> LN -> hyperbolic head (Poincare dists to prototypes) +
// euclidean logits.
// Key facts: softmax over length-1 axis == 1  =>  attn = v exactly.
// Outputs (f32, concatenated): hyp_logits[4096*10000], euc_logits[4096*10000],
// emb[4096*128].
// Strategy: bf16 MFMA (16x16x32) for all GEMMs, f32 everywhere else.
// ---------------------------------------------------------------------------

using bf16x8 = __attribute__((ext_vector_type(8))) __bf16;
using f32x4  = __attribute__((ext_vector_type(4))) float;

#define DEVINL __device__ __forceinline__

DEVINL unsigned short f2b(float f) {
    // round-to-nearest-even f32 -> bf16 (no NaN inputs in this problem)
    unsigned int u = __builtin_bit_cast(unsigned int, f);
    u = (u + 0x7fffu + ((u >> 16) & 1u)) >> 16;
    return (unsigned short)u;
}

DEVINL float gelu_exact(float x) {
    return 0.5f * x * (1.0f + erff(x * 0.70710678118654752440f));
}

DEVINL float wave_sum(float v) {
    #pragma unroll
    for (int m = 32; m > 0; m >>= 1) v += __shfl_xor(v, m, 64);
    return v;
}

DEVINL float get_c(const float* logc) {
    float c = expf(logc[0]);
    c = fminf(fmaxf(c, 1e-4f), 10.0f);
    return fmaxf(fabsf(c), 1e-6f);
}

// --------------------------- prep kernels ----------------------------------

__global__ void k_cvt_bf16(const float* __restrict__ src,
                           unsigned short* __restrict__ dst, int n) {
    int i = blockIdx.x * 256 + threadIdx.x;
    if (i < n) dst[i] = f2b(src[i]);
}

// dst[n][k] = src[k][off + n]; dst is Npad x K bf16 (rows n >= N zero-filled)
__global__ void k_transpose_cvt(const float* __restrict__ src,
                                unsigned short* __restrict__ dst,
                                int K, int N, int Npad, int ld, int off) {
    __shared__ float tile[32][33];
    int kb = blockIdx.x * 32, nb = blockIdx.y * 32;
    int tx = threadIdx.x & 31, ty = threadIdx.x >> 5;  // 32 x 8
    #pragma unroll
    for (int i = 0; i < 32; i += 8) {
        int k = kb + ty + i, n = nb + tx;
        tile[ty + i][tx] = (k < K && n < N) ? src[(size_t)k * ld + off + n] : 0.0f;
    }
    __syncthreads();
    #pragma unroll
    for (int i = 0; i < 32; i += 8) {
        int n = nb + ty + i, k = kb + tx;
        if (n < Npad && k < K) dst[(size_t)n * K + k] = f2b(tile[tx][ty + i]);
    }
}

// prototypes: clip to Poincare ball, emit bf16 rows + p2 + dp (pad rows zeroed)
__global__ void k_protos(const float* __restrict__ P, const float* __restrict__ logc,
                         unsigned short* __restrict__ pH, float* __restrict__ p2a,
                         float* __restrict__ dpa, int Crows, int Cpad) {
    int lane = threadIdx.x & 63;
    int row = blockIdx.x * 4 + (threadIdx.x >> 6);
    if (row >= Cpad) return;
    size_t base = (size_t)row * 128;
    if (row < Crows) {
        float a = P[base + lane], b = P[base + 64 + lane];
        float n2 = wave_sum(a * a + b * b);
        float c = get_c(logc);
        float sq = sqrtf(c);
        float mx = (1.0f - 1e-5f) / sq;
        float pn = sqrtf(n2);
        float f = fminf(mx / fmaxf(pn, 1e-6f), 1.0f);
        a *= f; b *= f;
        pH[base + lane] = f2b(a); pH[base + 64 + lane] = f2b(b);
        if (lane == 0) {
            float p2 = n2 * f * f;
            p2a[row] = p2;
            dpa[row] = 1.0f - c * fminf(p2, 1.0f - 1e-5f);
        }
    } else {
        pH[base + lane] = 0; pH[base + 64 + lane] = 0;
        if (lane == 0) { p2a[row] = 0.0f; dpa[row] = 1.0f; }
    }
}

// --------------------------- LN kernels ------------------------------------

__global__ void k_ln1(const float* __restrict__ t, const float* __restrict__ ao,
                      const float* __restrict__ g, const float* __restrict__ bt,
                      float* __restrict__ outF, unsigned short* __restrict__ outH) {
    int lane = threadIdx.x & 63;
    int row = blockIdx.x * 4 + (threadIdx.x >> 6);
    size_t base = (size_t)row * 128;
    float a = t[base + lane] + ao[base + lane];
    float b = t[base + 64 + lane] + ao[base + 64 + lane];
    float m = wave_sum(a + b) * (1.0f / 128.0f);
    float da = a - m, db = b - m;
    float var = wave_sum(da * da + db * db) * (1.0f / 128.0f);
    float inv = 1.0f / sqrtf(var + 1e-5f);
    float ya = da * inv * g[lane] + bt[lane];
    float yb = db * inv * g[64 + lane] + bt[64 + lane];
    outF[base + lane] = ya; outF[base + 64 + lane] = yb;
    outH[base + lane] = f2b(ya); outH[base + 64 + lane] = f2b(yb);
}

// LN2 + Poincare embedding: emits emb (f32 to d_out), emb bf16, t bf16, e2, de
__global__ void k_ln2_hyp(const float* __restrict__ xs1, const float* __restrict__ fo,
                          const float* __restrict__ g, const float* __restrict__ bt,
                          const float* __restrict__ logc,
                          float* __restrict__ embOut, unsigned short* __restrict__ embH,
                          unsigned short* __restrict__ tH,
                          float* __restrict__ e2a, float* __restrict__ dea) {
    int lane = threadIdx.x & 63;
    int row = blockIdx.x * 4 + (threadIdx.x >> 6);
    size_t base = (size_t)row * 128;
    float a = xs1[base + lane] + fo[base + lane];
    float b = xs1[base + 64 + lane] + fo[base + 64 + lane];
    float m = wave_sum(a + b) * (1.0f / 128.0f);
    float da = a - m, db = b - m;
    float var = wave_sum(da * da + db * db) * (1.0f / 128.0f);
    float inv = 1.0f / sqrtf(var + 1e-5f);
    float ya = da * inv * g[lane] + bt[lane];
    float yb = db * inv * g[64 + lane] + bt[64 + lane];
    tH[base + lane] = f2b(ya); tH[base + 64 + lane] = f2b(yb);
    float c = get_c(logc);
    float sq = sqrtf(c);
    float vn2 = wave_sum(ya * ya + yb * yb);
    float vn = fmaxf(sqrtf(vn2), 1e-10f);
    float s = tanhf(0.5f * sq * vn) / (sq * vn);
    float ea = ya * s, eb = yb * s;
    float en2 = wave_sum(ea * ea + eb * eb);
    float en = sqrtf(en2);
    float mx = (1.0f - 1e-5f) / sq;
    float f = fminf(mx / fmaxf(en, 1e-6f), 1.0f);
    ea *= f; eb *= f;
    embOut[base + lane] = ea; embOut[base + 64 + lane] = eb;
    embH[base + lane] = f2b(ea); embH[base + 64 + lane] = f2b(eb);
    if (lane == 0) {
        float e2 = en2 * f * f;
        e2a[row] = e2;
        dea[row] = 1.0f - c * fminf(e2, 1.0f - 1e-5f);
    }
}

// --------------------------- MFMA GEMM -------------------------------------
// C[M x N] = A[M x K] * B[N x K]^T   (both bf16, K-contiguous, f32 accum)
// 128x128 tile, BK=64, 256 threads = 4 waves, each wave a 64x64 quadrant.
// EP: 0 = +bias -> bf16 | 1 = gelu(+bias) -> bf16 | 2 = +bias -> f32
//     3 = +bias -> f32 AND bf16 | 4 = euclid (+bias, masked f32)
//     5 = hyperbolic distance epilogue (masked f32)
template <int EP>
__global__ __launch_bounds__(256) void k_gemm_nt(
    const unsigned short* __restrict__ A, const unsigned short* __restrict__ Bm,
    const float* __restrict__ bias, float* __restrict__ outF,
    unsigned short* __restrict__ outH, int K, int Nstore,
    const float* __restrict__ e2, const float* __restrict__ de,
    const float* __restrict__ p2, const float* __restrict__ dp,
    const float* __restrict__ logc) {
    __shared__ __align__(16) unsigned short As[128 * 64];
    __shared__ __align__(16) unsigned short Bs[128 * 64];
    const int tid = threadIdx.x;
    const int lane = tid & 63;
    const int wid = tid >> 6;
    const int row0 = blockIdx.x * 128;
    const int col0 = blockIdx.y * 128;
    const int q = lane >> 4;    // quad within wave
    const int l16 = lane & 15;
    const int wm = (wid >> 1) * 64;
    const int wn = (wid & 1) * 64;

    f32x4 acc[4][4];
    #pragma unroll
    for (int i = 0; i < 4; i++)
        #pragma unroll
        for (int j = 0; j < 4; j++) acc[i][j] = {0.f, 0.f, 0.f, 0.f};

    for (int k0 = 0; k0 < K; k0 += 64) {
        #pragma unroll
        for (int it = 0; it < 4; it++) {
            int idx = it * 256 + tid;
            int r = idx >> 3;
            int ck = (idx & 7) * 8;
            *(uint4*)&As[r * 64 + ck] =
                *(const uint4*)&A[(size_t)(row0 + r) * K + k0 + ck];
            *(uint4*)&Bs[r * 64 + ck] =
                *(const uint4*)&Bm[(size_t)(col0 + r) * K + k0 + ck];
        }
        __syncthreads();
        #pragma unroll
        for (int kk = 0; kk < 64; kk += 32) {
            bf16x8 af[4], bfr[4];
            #pragma unroll
            for (int i = 0; i < 4; i++)
                af[i] = *(const bf16x8*)&As[(wm + i * 16 + l16) * 64 + kk + q * 8];
            #pragma unroll
            for (int j = 0; j < 4; j++)
                bfr[j] = *(const bf16x8*)&Bs[(wn + j * 16 + l16) * 64 + kk + q * 8];
            #pragma unroll
            for (int i = 0; i < 4; i++)
                #pragma unroll
                for (int j = 0; j < 4; j++)
                    acc[i][j] = __builtin_amdgcn_mfma_f32_16x16x32_bf16(
                        af[i], bfr[j], acc[i][j], 0, 0, 0);
        }
        __syncthreads();
    }

    float inv_sq = 0.f;
    if (EP == 5) { float c = get_c(logc); inv_sq = 2.0f / sqrtf(c); }

    // C/D layout (m89-verified): col = lane&15, row = (lane>>4)*4 + reg
    #pragma unroll
    for (int i = 0; i < 4; i++) {
        #pragma unroll
        for (int j = 0; j < 4; j++) {
            int col = col0 + wn + j * 16 + l16;
            #pragma unroll
            for (int rg = 0; rg < 4; rg++) {
                int row = row0 + wm + i * 16 + q * 4 + rg;
                float v = acc[i][j][rg];
                if (EP == 0) {
                    v += bias[col];
                    outH[(size_t)row * Nstore + col] = f2b(v);
                } else if (EP == 1) {
                    v = gelu_exact(v + bias[col]);
                    outH[(size_t)row * Nstore + col] = f2b(v);
                } else if (EP == 2) {
                    v += bias[col];
                    outF[(size_t)row * Nstore + col] = v;
                } else if (EP == 3) {
                    v += bias[col];
                    outF[(size_t)row * Nstore + col] = v;
                    outH[(size_t)row * Nstore + col] = f2b(v);
                } else if (EP == 4) {
                    if (col < Nstore)
                        outF[(size_t)row * Nstore + col] = v + bias[col];
                } else {  // EP == 5: hyperbolic distance
                    if (col < Nstore) {
                        float diff = fmaxf(e2[row] + p2[col] - 2.0f * v, 1e-10f);
                        float den = fmaxf(de[row] * dp[col], 1e-6f);
                        float arg = fmaxf(1.0f + 2.0f * diff / den, 1.0f + 1e-6f);
                        outF[(size_t)row * Nstore + col] = -inv_sq * acoshf(arg);
                    }
                }
            }
        }
    }
}

// --------------------------- launcher --------------------------------------

extern "C" void kernel_launch(void* const* d_in, const int* in_sizes, int n_in,
                              void* d_out, int out_size, void* d_ws, size_t ws_size,
                              hipStream_t stream) {
    const float* x      = (const float*)d_in[0];
    const float* W1     = (const float*)d_in[1];
    const float* b1     = (const float*)d_in[2];
    const float* W2     = (const float*)d_in[3];
    const float* b2     = (const float*)d_in[4];
    const float* in_w   = (const float*)d_in[5];
    const float* in_b   = (const float*)d_in[6];
    const float* out_w  = (const float*)d_in[7];
    const float* out_b  = (const float*)d_in[8];
    const float* fw1    = (const float*)d_in[9];
    const float* fb1    = (const float*)d_in[10];
    const float* fw2    = (const float*)d_in[11];
    const float* fb2    = (const float*)d_in[12];
    const float* g1     = (const float*)d_in[13];
    const float* bt1    = (const float*)d_in[14];
    const float* g2     = (const float*)d_in[15];
    const float* bt2    = (const float*)d_in[16];
    const float* logc   = (const float*)d_in[17];
    const float* protos = (const float*)d_in[18];
    const float* euc_w  = (const float*)d_in[19];
    const float* euc_b  = (const float*)d_in[20];

    float* out_hyp = (float*)d_out;
    float* out_euc = out_hyp + (size_t)4096 * 10000;
    float* out_emb = out_euc + (size_t)4096 * 10000;

    // workspace layout (bytes), ~33 MB total
    constexpr size_t O_XBF   = 0;                               // 4096x1024 bf16
    constexpr size_t O_W1T   = O_XBF   + (size_t)4096 * 1024 * 2;
    constexpr size_t O_W2T   = O_W1T   + (size_t)256 * 1024 * 2;
    constexpr size_t O_INWVT = O_W2T   + (size_t)128 * 256 * 2;
    constexpr size_t O_OUTWT = O_INWVT + (size_t)128 * 128 * 2;
    constexpr size_t O_FW1T  = O_OUTWT + (size_t)128 * 128 * 2;
    constexpr size_t O_FW2T  = O_FW1T  + (size_t)512 * 128 * 2;
    constexpr size_t O_EUCWT = O_FW2T  + (size_t)128 * 512 * 2;
    constexpr size_t O_PROTB = O_EUCWT + (size_t)10112 * 128 * 2;
    constexpr size_t O_HBF   = O_PROTB + (size_t)10112 * 128 * 2;
    constexpr size_t O_TF    = O_HBF   + (size_t)4096 * 256 * 2;
    constexpr size_t O_TBF   = O_TF    + (size_t)4096 * 128 * 4;
    constexpr size_t O_VBF   = O_TBF   + (size_t)4096 * 128 * 2;
    constexpr size_t O_AO    = O_VBF   + (size_t)4096 * 128 * 2;
    constexpr size_t O_XS1F  = O_AO    + (size_t)4096 * 128 * 4;
    constexpr size_t O_XS1B  = O_XS1F  + (size_t)4096 * 128 * 4;
    constexpr size_t O_FHB   = O_XS1B  + (size_t)4096 * 128 * 2;
    constexpr size_t O_FOF   = O_FHB   + (size_t)4096 * 512 * 2;
    constexpr size_t O_TFB   = O_FOF   + (size_t)4096 * 128 * 4;
    constexpr size_t O_EMBB  = O_TFB   + (size_t)4096 * 128 * 2;
    constexpr size_t O_E2    = O_EMBB  + (size_t)4096 * 128 * 2;
    constexpr size_t O_DE    = O_E2    + (size_t)4096 * 4;
    constexpr size_t O_P2    = O_DE    + (size_t)4096 * 4;
    constexpr size_t O_DP    = O_P2    + (size_t)10112 * 4;

    char* w = (char*)d_ws;
    auto US = [&](size_t o) { return (unsigned short*)(w + o); };
    auto FP = [&](size_t o) { return (float*)(w + o); };

    // ---- prep: bf16 convert x; transpose-convert weights into N x K bf16 ----
    k_cvt_bf16<<<(4096 * 1024 + 255) / 256, 256, 0, stream>>>(x, US(O_XBF), 4096 * 1024);
    k_transpose_cvt<<<dim3(32, 8),   256, 0, stream>>>(W1,    US(O_W1T),   1024, 256, 256, 256, 0);
    k_transpose_cvt<<<dim3(8, 4),    256, 0, stream>>>(W2,    US(O_W2T),   256, 128, 128, 128, 0);
    k_transpose_cvt<<<dim3(4, 4),    256, 0, stream>>>(in_w,  US(O_INWVT), 128, 128, 128, 384, 256); // v-slice only
    k_transpose_cvt<<<dim3(4, 4),    256, 0, stream>>>(out_w, US(O_OUTWT), 128, 128, 128, 128, 0);
    k_transpose_cvt<<<dim3(4, 16),   256, 0, stream>>>(fw1,   US(O_FW1T),  128, 512, 512, 512, 0);
    k_transpose_cvt<<<dim3(16, 4),   256, 0, stream>>>(fw2,   US(O_FW2T),  512, 128, 128, 128, 0);
    k_transpose_cvt<<<dim3(4, 316),  256, 0, stream>>>(euc_w, US(O_EUCWT), 128, 10000, 10112, 10000, 0);
    k_protos<<<2528, 256, 0, stream>>>(protos, logc, US(O_PROTB), FP(O_P2), FP(O_DP), 10000, 10112);

    // ---- trunk ----
    // t = gelu(x@W1+b1)@W2 + b2
    k_gemm_nt<1><<<dim3(32, 2), 256, 0, stream>>>(US(O_XBF), US(O_W1T), b1, nullptr, US(O_HBF),
                                                  1024, 256, nullptr, nullptr, nullptr, nullptr, nullptr);
    k_gemm_nt<3><<<dim3(32, 1), 256, 0, stream>>>(US(O_HBF), US(O_W2T), b2, FP(O_TF), US(O_TBF),
                                                  256, 128, nullptr, nullptr, nullptr, nullptr, nullptr);
    // attn == v (softmax over singleton); v = t@in_w[:,256:384]+in_b[256:]
    k_gemm_nt<0><<<dim3(32, 1), 256, 0, stream>>>(US(O_TBF), US(O_INWVT), in_b + 256, nullptr, US(O_VBF),
                                                  128, 128, nullptr, nullptr, nullptr, nullptr, nullptr);
    k_gemm_nt<2><<<dim3(32, 1), 256, 0, stream>>>(US(O_VBF), US(O_OUTWT), out_b, FP(O_AO), nullptr,
                                                  128, 128, nullptr, nullptr, nullptr, nullptr, nullptr);
    k_ln1<<<1024, 256, 0, stream>>>(FP(O_TF), FP(O_AO), g1, bt1, FP(O_XS1F), US(O_XS1B));
    // FFN
    k_gemm_nt<1><<<dim3(32, 4), 256, 0, stream>>>(US(O_XS1B), US(O_FW1T), fb1, nullptr, US(O_FHB),
                                                  128, 512, nullptr, nullptr, nullptr, nullptr, nullptr);
    k_gemm_nt<2><<<dim3(32, 1), 256, 0, stream>>>(US(O_FHB), US(O_FW2T), fb2, FP(O_FOF), nullptr,
                                                  512, 128, nullptr, nullptr, nullptr, nullptr, nullptr);
    k_ln2_hyp<<<1024, 256, 0, stream>>>(FP(O_XS1F), FP(O_FOF), g2, bt2, logc,
                                        out_emb, US(O_EMBB), US(O_TFB), FP(O_E2), FP(O_DE));

    // ---- heads: 4096 x 10000, K=128 ----
    k_gemm_nt<5><<<dim3(32, 79), 256, 0, stream>>>(US(O_EMBB), US(O_PROTB), nullptr, out_hyp, nullptr,
                                                   128, 10000, FP(O_E2), FP(O_DE), FP(O_P2), FP(O_DP), logc);
    k_gemm_nt<4><<<dim3(32, 79), 256, 0, stream>>>(US(O_TFB), US(O_EUCWT), euc_b, out_euc, nullptr,
                                                   128, 10000, nullptr, nullptr, nullptr, nullptr, nullptr);
}

// Round 2
// 584.981 us; speedup vs baseline: 1.2172x; 1.2172x over previous
//
#include <hip/hip_runtime.h>
#include <cmath>

// ---------------------------------------------------------------------------
// HyperbolicScaleHead — round 2.
// Structure: softmax over seqlen-1 == identity => attn_out = t@(Wv@Wo)+b.
// Further fold: LN1 input = t@(I+Wv@Wo)+bc and t = h@W2+b2, so
//   pre1 = h @ (W2@(I+Wv@Wo)) + (b2@(I+Wv@Wo)+bc)   -- one GEMM, LN1 fused.
// Pipeline (8 launches):
//   k_prep   : cvt x->bf16, transpose W1/fw1/fw2/euc_w, protos clip+norms
//   k_fold1  : Wc' = I + Wv@Wo (f32), bc = bv@Wo + out_b
//   k_fold2  : W2''^T = (W2@Wc')^T bf16 (NxK), b'' = b2@Wc' + bc
//   GEMM1    : gelu(x@W1+b1) -> bf16               (4096x256x1024)
//   GEMM2    : h@W2''+b'' -> LN1 epilogue          (4096x128x256)
//   FFN1     : gelu(xs1@fw1+fb1) -> bf16           (4096x512x128)
//   FFN2     : xs1 + h2@fw2+fb2 -> LN2+Poincare    (4096x128x512)
//   k_heads  : hyp + euc logits fused              (4096x(2x10112)x128)
// All GEMMs: 128x128 tile, 4 waves, 16x16x32 bf16 MFMA, global_load_lds x16.
// ---------------------------------------------------------------------------

using bf16x8 = __attribute__((ext_vector_type(8))) __bf16;
using f32x4  = __attribute__((ext_vector_type(4))) float;

#define DEVINL __device__ __forceinline__

DEVINL unsigned short f2b(float f) {
    unsigned int u = __builtin_bit_cast(unsigned int, f);
    u = (u + 0x7fffu + ((u >> 16) & 1u)) >> 16;
    return (unsigned short)u;
}

DEVINL float gelu_exact(float x) {
    return 0.5f * x * (1.0f + erff(x * 0.70710678118654752440f));
}

DEVINL float get_c(const float* logc) {
    float c = expf(logc[0]);
    c = fminf(fmaxf(c, 1e-4f), 10.0f);
    return fmaxf(fabsf(c), 1e-6f);
}

DEVINL void async16(const unsigned short* g, unsigned short* l) {
    __builtin_amdgcn_global_load_lds(
        (const __attribute__((address_space(1))) void*)g,
        (__attribute__((address_space(3))) void*)l, 16, 0, 0);
}

// --------------------------- prep mega-kernel ------------------------------

DEVINL void t_cvt(const float* __restrict__ src, unsigned short* __restrict__ dst,
                  int K, int N, int Npad, int ld, int off, int tblk, int tid,
                  float tile[32][33]) {
    int kbCount = K >> 5;
    int kb = (tblk % kbCount) * 32, nb = (tblk / kbCount) * 32;
    int tx = tid & 31, ty = tid >> 5;
    #pragma unroll
    for (int i = 0; i < 32; i += 8) {
        int k = kb + ty + i, n = nb + tx;
        tile[ty + i][tx] = (k < K && n < N) ? src[(size_t)k * ld + off + n] : 0.0f;
    }
    __syncthreads();
    #pragma unroll
    for (int i = 0; i < 32; i += 8) {
        int n = nb + ty + i, k = kb + tx;
        if (n < Npad && k < K) dst[(size_t)n * K + k] = f2b(tile[tx][ty + i]);
    }
}

// block ranges: [0,4096) cvt x | +256 W1 | +64 fw1 | +64 fw2 | +1264 euc_w | +2528 protos
#define PB0 4096
#define PB1 (PB0 + 256)
#define PB2 (PB1 + 64)
#define PB3 (PB2 + 64)
#define PB4 (PB3 + 1264)
#define PB5 (PB4 + 2528)

__global__ void k_prep(const float* __restrict__ x, const float* __restrict__ W1,
                       const float* __restrict__ fw1, const float* __restrict__ fw2,
                       const float* __restrict__ euc_w, const float* __restrict__ P,
                       const float* __restrict__ logc,
                       unsigned short* __restrict__ xbf, unsigned short* __restrict__ W1T,
                       unsigned short* __restrict__ FW1T, unsigned short* __restrict__ FW2T,
                       unsigned short* __restrict__ EUCWT, unsigned short* __restrict__ PROTB,
                       float* __restrict__ p2a, float* __restrict__ dpa) {
    __shared__ float tile[32][33];
    int b = blockIdx.x, tid = threadIdx.x;
    if (b < PB0) {
        int i = b * 256 + tid;
        float4 v = ((const float4*)x)[i];
        ushort4 o;
        o.x = f2b(v.x); o.y = f2b(v.y); o.z = f2b(v.z); o.w = f2b(v.w);
        ((ushort4*)xbf)[i] = o;
    } else if (b < PB1) {
        t_cvt(W1, W1T, 1024, 256, 256, 256, 0, b - PB0, tid, tile);
    } else if (b < PB2) {
        t_cvt(fw1, FW1T, 128, 512, 512, 512, 0, b - PB1, tid, tile);
    } else if (b < PB3) {
        t_cvt(fw2, FW2T, 512, 128, 128, 128, 0, b - PB2, tid, tile);
    } else if (b < PB4) {
        t_cvt(euc_w, EUCWT, 128, 10000, 10112, 10000, 0, b - PB3, tid, tile);
    } else {
        int lane = tid & 63;
        int row = (b - PB4) * 4 + (tid >> 6);
        size_t base = (size_t)row * 128;
        if (row < 10000) {
            float a = P[base + lane], bb = P[base + 64 + lane];
            float n2 = a * a + bb * bb;
            #pragma unroll
            for (int m = 32; m > 0; m >>= 1) n2 += __shfl_xor(n2, m, 64);
            float c = get_c(logc);
            float sq = sqrtf(c);
            float mx = (1.0f - 1e-5f) / sq;
            float pn = sqrtf(n2);
            float f = fminf(mx / fmaxf(pn, 1e-6f), 1.0f);
            a *= f; bb *= f;
            PROTB[base + lane] = f2b(a); PROTB[base + 64 + lane] = f2b(bb);
            if (lane == 0) {
                float p2 = n2 * f * f;
                p2a[row] = p2;
                dpa[row] = 1.0f - c * fminf(p2, 1.0f - 1e-5f);
            }
        } else if (row < 10112) {
            PROTB[base + lane] = 0; PROTB[base + 64 + lane] = 0;
            if (lane == 0) { p2a[row] = 0.0f; dpa[row] = 1.0f; }
        }
    }
}

// --------------------------- fold kernels ----------------------------------

// Wc' = I + in_w[:,256:384] @ out_w ; bc = in_b[256:] @ out_w + out_b
__global__ void k_fold1(const float* __restrict__ in_w, const float* __restrict__ in_b,
                        const float* __restrict__ out_w, const float* __restrict__ out_b,
                        float* __restrict__ Wc, float* __restrict__ bc) {
    int n = threadIdx.x, k = blockIdx.x;
    if (k < 128) {
        float a = 0.f;
        for (int j = 0; j < 128; j++) a += in_w[k * 384 + 256 + j] * out_w[j * 128 + n];
        Wc[k * 128 + n] = a + ((k == n) ? 1.0f : 0.0f);
    } else {
        float a = 0.f;
        for (int j = 0; j < 128; j++) a += in_b[256 + j] * out_w[j * 128 + n];
        bc[n] = a + out_b[n];
    }
}

// W2''^T (NxK bf16, N=128,K=256) = (W2 @ Wc')^T ; b'' = b2 @ Wc' + bc
__global__ void k_fold2(const float* __restrict__ W2, const float* __restrict__ b2,
                        const float* __restrict__ Wc, const float* __restrict__ bc,
                        unsigned short* __restrict__ W2ppT, float* __restrict__ bpp) {
    int n = threadIdx.x, k = blockIdx.x;
    if (k < 256) {
        float a = 0.f;
        for (int j = 0; j < 128; j++) a += W2[k * 128 + j] * Wc[j * 128 + n];
        W2ppT[n * 256 + k] = f2b(a);
    } else {
        float a = 0.f;
        for (int j = 0; j < 128; j++) a += b2[j] * Wc[j * 128 + n];
        bpp[n] = a + bc[n];
    }
}

// --------------------------- GEMM + fused epilogues ------------------------
// C[Mx128block] = A[MxK] * B[NxK]^T, 128x128 tile, 4 waves (64x64 quadrants).
// EP 0: gelu(v+bias) -> bf16
// EP 1: LN1(v+bias) -> f32 + bf16           (requires N==128, gridDim.y==1)
// EP 2: LN2(v+bias+res) -> Poincare embed   (requires N==128, gridDim.y==1)
#define EP_GELU 0
#define EP_LN1 1
#define EP_LN2HYP 2

template <int EP, int BK>
__global__ __launch_bounds__(256) void k_gemm(
    const unsigned short* __restrict__ A, const unsigned short* __restrict__ Bm,
    const float* __restrict__ bias, int K, int Nstore,
    float* __restrict__ outF, unsigned short* __restrict__ outH,
    const float* __restrict__ g, const float* __restrict__ bt,
    const float* __restrict__ resF, const float* __restrict__ logc,
    float* __restrict__ embF, unsigned short* __restrict__ embH,
    float* __restrict__ e2a, float* __restrict__ dea) {
    __shared__ __align__(16) unsigned short As[128 * BK];
    __shared__ __align__(16) unsigned short Bs[128 * BK];
    const int tid = threadIdx.x, lane = tid & 63, wid = tid >> 6;
    const int row0 = blockIdx.x * 128, col0 = blockIdx.y * 128;
    const int q = lane >> 4, l16 = lane & 15;
    const int wm = (wid >> 1) * 64, wn = (wid & 1) * 64;
    constexpr int CPR = BK / 8;            // 16B chunks per row
    constexpr int ITER = 128 * CPR / 256;  // staging iters per tile

    f32x4 acc[4][4];
    #pragma unroll
    for (int i = 0; i < 4; i++)
        #pragma unroll
        for (int j = 0; j < 4; j++) acc[i][j] = {0.f, 0.f, 0.f, 0.f};

    for (int k0 = 0; k0 < K; k0 += BK) {
        #pragma unroll
        for (int it = 0; it < ITER; ++it) {
            int idx = it * 256 + tid;
            int r = idx / CPR, ck = (idx % CPR) * 8;
            async16(&A[(size_t)(row0 + r) * K + k0 + ck], &As[idx * 8]);
        }
        #pragma unroll
        for (int it = 0; it < ITER; ++it) {
            int idx = it * 256 + tid;
            int r = idx / CPR, ck = (idx % CPR) * 8;
            async16(&Bm[(size_t)(col0 + r) * K + k0 + ck], &Bs[idx * 8]);
        }
        __syncthreads();
        #pragma unroll
        for (int kk = 0; kk < BK; kk += 32) {
            bf16x8 af[4], bfr[4];
            #pragma unroll
            for (int i = 0; i < 4; i++)
                af[i] = *(const bf16x8*)&As[(wm + i * 16 + l16) * BK + kk + q * 8];
            #pragma unroll
            for (int j = 0; j < 4; j++)
                bfr[j] = *(const bf16x8*)&Bs[(wn + j * 16 + l16) * BK + kk + q * 8];
            #pragma unroll
            for (int i = 0; i < 4; i++)
                #pragma unroll
                for (int j = 0; j < 4; j++)
                    acc[i][j] = __builtin_amdgcn_mfma_f32_16x16x32_bf16(
                        af[i], bfr[j], acc[i][j], 0, 0, 0);
        }
        __syncthreads();
    }

    // C/D layout (m89): col = l16 (+16j +wn), row = q*4 + rg (+16i +wm)
    if (EP == EP_GELU) {
        #pragma unroll
        for (int j = 0; j < 4; j++) {
            int col = col0 + wn + j * 16 + l16;
            float bb = bias[col];
            #pragma unroll
            for (int i = 0; i < 4; i++)
                #pragma unroll
                for (int rg = 0; rg < 4; rg++) {
                    int row = row0 + wm + i * 16 + q * 4 + rg;
                    outH[(size_t)row * Nstore + col] = f2b(gelu_exact(acc[i][j][rg] + bb));
                }
        }
        return;
    }

    // ---- LN epilogues (full row inside the block; 2 waves share each row) ----
    // add bias (+ residual for LN2) into acc
    #pragma unroll
    for (int j = 0; j < 4; j++) {
        int col = wn + j * 16 + l16;
        float bb = bias[col];
        #pragma unroll
        for (int i = 0; i < 4; i++)
            #pragma unroll
            for (int rg = 0; rg < 4; rg++) {
                int rl = wm + i * 16 + q * 4 + rg;
                float v = acc[i][j][rg] + bb;
                if (EP == EP_LN2HYP) v += resF[(size_t)(row0 + rl) * 128 + col];
                acc[i][j][rg] = v;
            }
    }
    float* sred = (float*)As;  // 128 rows x {sum0, sq0, sum1, sq1}
    #pragma unroll
    for (int i = 0; i < 4; i++)
        #pragma unroll
        for (int rg = 0; rg < 4; rg++) {
            float s = 0.f, ss = 0.f;
            #pragma unroll
            for (int j = 0; j < 4; j++) { float v = acc[i][j][rg]; s += v; ss += v * v; }
            #pragma unroll
            for (int m = 1; m < 16; m <<= 1) {
                s += __shfl_xor(s, m, 64); ss += __shfl_xor(ss, m, 64);
            }
            if (l16 == 0) {
                int rl = wm + i * 16 + q * 4 + rg;
                sred[rl * 4 + (wid & 1) * 2] = s;
                sred[rl * 4 + (wid & 1) * 2 + 1] = ss;
            }
        }
    __syncthreads();

    float c = 0.f, sq = 0.f, mx = 0.f;
    if (EP == EP_LN2HYP) { c = get_c(logc); sq = sqrtf(c); mx = (1.0f - 1e-5f) / sq; }

    #pragma unroll
    for (int i = 0; i < 4; i++)
        #pragma unroll
        for (int rg = 0; rg < 4; rg++) {
            int rl = wm + i * 16 + q * 4 + rg;
            int row = row0 + rl;
            float sum = sred[rl * 4 + 0] + sred[rl * 4 + 2];
            float sqs = sred[rl * 4 + 1] + sred[rl * 4 + 3];
            float m = sum * (1.0f / 128.0f);
            float var = sqs * (1.0f / 128.0f) - m * m;
            float inv = rsqrtf(var + 1e-5f);
            #pragma unroll
            for (int j = 0; j < 4; j++) {
                int col = wn + j * 16 + l16;
                float y = (acc[i][j][rg] - m) * inv * g[col] + bt[col];
                acc[i][j][rg] = y;
                if (EP == EP_LN1) {
                    outF[(size_t)row * 128 + col] = y;
                    outH[(size_t)row * 128 + col] = f2b(y);
                } else {
                    outH[(size_t)row * 128 + col] = f2b(y);  // tH
                }
            }
        }

    if (EP == EP_LN2HYP) {
        float* sred2 = (float*)Bs;  // 128 rows x {vn2_half0, vn2_half1}
        #pragma unroll
        for (int i = 0; i < 4; i++)
            #pragma unroll
            for (int rg = 0; rg < 4; rg++) {
                float s2 = 0.f;
                #pragma unroll
                for (int j = 0; j < 4; j++) { float y = acc[i][j][rg]; s2 += y * y; }
                #pragma unroll
                for (int m = 1; m < 16; m <<= 1) s2 += __shfl_xor(s2, m, 64);
                if (l16 == 0) {
                    int rl = wm + i * 16 + q * 4 + rg;
                    sred2[rl * 2 + (wid & 1)] = s2;
                }
            }
        __syncthreads();
        #pragma unroll
        for (int i = 0; i < 4; i++)
            #pragma unroll
            for (int rg = 0; rg < 4; rg++) {
                int rl = wm + i * 16 + q * 4 + rg;
                int row = row0 + rl;
                float vn2 = sred2[rl * 2] + sred2[rl * 2 + 1];
                float vn = fmaxf(sqrtf(vn2), 1e-10f);
                float sc = tanhf(0.5f * sq * vn) / (sq * vn);
                float en2 = sc * sc * vn2;
                float en = sqrtf(en2);
                float f = fminf(mx / fmaxf(en, 1e-6f), 1.0f);
                float scale = sc * f;
                float e2v = en2 * f * f;
                #pragma unroll
                for (int j = 0; j < 4; j++) {
                    int col = wn + j * 16 + l16;
                    float e = acc[i][j][rg] * scale;
                    embF[(size_t)row * 128 + col] = e;
                    embH[(size_t)row * 128 + col] = f2b(e);
                }
                if (l16 == 0 && (wid & 1) == 0) {
                    e2a[row] = e2v;
                    dea[row] = 1.0f - c * fminf(e2v, 1.0f - 1e-5f);
                }
            }
    }
}

// --------------------------- fused heads -----------------------------------
// grid (32, 158): y<79 -> hyperbolic head, else euclidean. K=128 single-stage.
__global__ __launch_bounds__(256) void k_heads(
    const unsigned short* __restrict__ embH, const unsigned short* __restrict__ tH,
    const unsigned short* __restrict__ protB, const unsigned short* __restrict__ eucWT,
    const float* __restrict__ e2a, const float* __restrict__ dea,
    const float* __restrict__ p2a, const float* __restrict__ dpa,
    const float* __restrict__ euc_b, const float* __restrict__ logc,
    float* __restrict__ outHyp, float* __restrict__ outEuc) {
    __shared__ __align__(16) unsigned short S[4096 * 8];  // 64 KB: A tile + B tile
    const bool hyp = blockIdx.y < 79;
    const int cb = hyp ? blockIdx.y : blockIdx.y - 79;
    const unsigned short* Ap = hyp ? embH : tH;
    const unsigned short* Bp = hyp ? protB : eucWT;
    const int tid = threadIdx.x, lane = tid & 63, wid = tid >> 6;
    const int row0 = blockIdx.x * 128, col0 = cb * 128;
    const int q = lane >> 4, l16 = lane & 15;
    const int wm = (wid >> 1) * 64, wn = (wid & 1) * 64;

    #pragma unroll
    for (int it = 0; it < 16; ++it) {
        int idx = it * 256 + tid;
        if (idx < 2048) {
            int r = idx >> 4, ck = (idx & 15) * 8;
            async16(&Ap[(size_t)(row0 + r) * 128 + ck], &S[idx * 8]);
        } else {
            int idb = idx - 2048;
            int r = idb >> 4, ck = (idb & 15) * 8;
            async16(&Bp[(size_t)(col0 + r) * 128 + ck], &S[idx * 8]);
        }
    }
    __syncthreads();
    const unsigned short* As = S;
    const unsigned short* Bs = S + 2048 * 8;

    f32x4 acc[4][4];
    #pragma unroll
    for (int i = 0; i < 4; i++)
        #pragma unroll
        for (int j = 0; j < 4; j++) acc[i][j] = {0.f, 0.f, 0.f, 0.f};
    #pragma unroll
    for (int kk = 0; kk < 128; kk += 32) {
        bf16x8 af[4], bfr[4];
        #pragma unroll
        for (int i = 0; i < 4; i++)
            af[i] = *(const bf16x8*)&As[(wm + i * 16 + l16) * 128 + kk + q * 8];
        #pragma unroll
        for (int j = 0; j < 4; j++)
            bfr[j] = *(const bf16x8*)&Bs[(wn + j * 16 + l16) * 128 + kk + q * 8];
        #pragma unroll
        for (int i = 0; i < 4; i++)
            #pragma unroll
            for (int j = 0; j < 4; j++)
                acc[i][j] = __builtin_amdgcn_mfma_f32_16x16x32_bf16(
                    af[i], bfr[j], acc[i][j], 0, 0, 0);
    }

    if (hyp) {
        float c = get_c(logc);
        float invsq = 2.0f / sqrtf(c);
        #pragma unroll
        for (int j = 0; j < 4; j++) {
            int col = col0 + wn + j * 16 + l16;
            if (col < 10000) {
                float p2v = p2a[col], dpv = dpa[col];
                #pragma unroll
                for (int i = 0; i < 4; i++)
                    #pragma unroll
                    for (int rg = 0; rg < 4; rg++) {
                        int row = row0 + wm + i * 16 + q * 4 + rg;
                        float v = acc[i][j][rg];
                        float diff = fmaxf(e2a[row] + p2v - 2.0f * v, 1e-10f);
                        float den = fmaxf(dea[row] * dpv, 1e-6f);
                        float arg = fmaxf(1.0f + 2.0f * diff / den, 1.0f + 1e-6f);
                        float d = __logf(arg + sqrtf(arg * arg - 1.0f));
                        outHyp[(size_t)row * 10000 + col] = -invsq * d;
                    }
            }
        }
    } else {
        #pragma unroll
        for (int j = 0; j < 4; j++) {
            int col = col0 + wn + j * 16 + l16;
            if (col < 10000) {
                float bb = euc_b[col];
                #pragma unroll
                for (int i = 0; i < 4; i++)
                    #pragma unroll
                    for (int rg = 0; rg < 4; rg++) {
                        int row = row0 + wm + i * 16 + q * 4 + rg;
                        outEuc[(size_t)row * 10000 + col] = acc[i][j][rg] + bb;
                    }
            }
        }
    }
}

// --------------------------- launcher --------------------------------------

extern "C" void kernel_launch(void* const* d_in, const int* in_sizes, int n_in,
                              void* d_out, int out_size, void* d_ws, size_t ws_size,
                              hipStream_t stream) {
    const float* x      = (const float*)d_in[0];
    const float* W1     = (const float*)d_in[1];
    const float* b1     = (const float*)d_in[2];
    const float* W2     = (const float*)d_in[3];
    const float* b2     = (const float*)d_in[4];
    const float* in_w   = (const float*)d_in[5];
    const float* in_b   = (const float*)d_in[6];
    const float* out_w  = (const float*)d_in[7];
    const float* out_b  = (const float*)d_in[8];
    const float* fw1    = (const float*)d_in[9];
    const float* fb1    = (const float*)d_in[10];
    const float* fw2    = (const float*)d_in[11];
    const float* fb2    = (const float*)d_in[12];
    const float* g1     = (const float*)d_in[13];
    const float* bt1    = (const float*)d_in[14];
    const float* g2     = (const float*)d_in[15];
    const float* bt2    = (const float*)d_in[16];
    const float* logc   = (const float*)d_in[17];
    const float* protos = (const float*)d_in[18];
    const float* euc_w  = (const float*)d_in[19];
    const float* euc_b  = (const float*)d_in[20];

    float* out_hyp = (float*)d_out;
    float* out_euc = out_hyp + (size_t)4096 * 10000;
    float* out_emb = out_euc + (size_t)4096 * 10000;

    constexpr size_t O_XBF   = 0;                                   // 4096x1024 bf16
    constexpr size_t O_W1T   = O_XBF   + (size_t)4096 * 1024 * 2;   // 256x1024
    constexpr size_t O_FW1T  = O_W1T   + (size_t)256 * 1024 * 2;    // 512x128
    constexpr size_t O_FW2T  = O_FW1T  + (size_t)512 * 128 * 2;     // 128x512
    constexpr size_t O_EUCWT = O_FW2T  + (size_t)128 * 512 * 2;     // 10112x128
    constexpr size_t O_PROTB = O_EUCWT + (size_t)10112 * 128 * 2;   // 10112x128
    constexpr size_t O_WC    = O_PROTB + (size_t)10112 * 128 * 2;   // 128x128 f32
    constexpr size_t O_BC    = O_WC    + (size_t)128 * 128 * 4;     // 128 f32
    constexpr size_t O_W2PP  = O_BC    + (size_t)128 * 4;           // 128x256 bf16
    constexpr size_t O_BPP   = O_W2PP  + (size_t)128 * 256 * 2;     // 128 f32
    constexpr size_t O_HBF   = O_BPP   + (size_t)128 * 4;           // 4096x256 bf16
    constexpr size_t O_XS1F  = O_HBF   + (size_t)4096 * 256 * 2;    // 4096x128 f32
    constexpr size_t O_XS1B  = O_XS1F  + (size_t)4096 * 128 * 4;    // 4096x128 bf16
    constexpr size_t O_FHB   = O_XS1B  + (size_t)4096 * 128 * 2;    // 4096x512 bf16
    constexpr size_t O_TFB   = O_FHB   + (size_t)4096 * 512 * 2;    // 4096x128 bf16
    constexpr size_t O_EMBB  = O_TFB   + (size_t)4096 * 128 * 2;    // 4096x128 bf16
    constexpr size_t O_E2    = O_EMBB  + (size_t)4096 * 128 * 2;
    constexpr size_t O_DE    = O_E2    + (size_t)4096 * 4;
    constexpr size_t O_P2    = O_DE    + (size_t)4096 * 4;
    constexpr size_t O_DP    = O_P2    + (size_t)10112 * 4;

    char* w = (char*)d_ws;
    auto US = [&](size_t o) { return (unsigned short*)(w + o); };
    auto FP = [&](size_t o) { return (float*)(w + o); };

    k_prep<<<PB5, 256, 0, stream>>>(x, W1, fw1, fw2, euc_w, protos, logc,
                                    US(O_XBF), US(O_W1T), US(O_FW1T), US(O_FW2T),
                                    US(O_EUCWT), US(O_PROTB), FP(O_P2), FP(O_DP));
    k_fold1<<<129, 128, 0, stream>>>(in_w, in_b, out_w, out_b, FP(O_WC), FP(O_BC));
    k_fold2<<<257, 128, 0, stream>>>(W2, b2, FP(O_WC), FP(O_BC), US(O_W2PP), FP(O_BPP));

    // GEMM1: gelu(x@W1+b1) -> h bf16 [4096x256]
    k_gemm<EP_GELU, 64><<<dim3(32, 2), 256, 0, stream>>>(
        US(O_XBF), US(O_W1T), b1, 1024, 256, nullptr, US(O_HBF),
        nullptr, nullptr, nullptr, nullptr, nullptr, nullptr, nullptr, nullptr);
    // GEMM2: h@W2''+b'' -> LN1 -> xs1 (f32 + bf16) [4096x128]
    k_gemm<EP_LN1, 64><<<dim3(32, 1), 256, 0, stream>>>(
        US(O_HBF), US(O_W2PP), FP(O_BPP), 256, 128, FP(O_XS1F), US(O_XS1B),
        g1, bt1, nullptr, nullptr, nullptr, nullptr, nullptr, nullptr);
    // FFN1: gelu(xs1@fw1+fb1) -> h2 bf16 [4096x512]
    k_gemm<EP_GELU, 128><<<dim3(32, 4), 256, 0, stream>>>(
        US(O_XS1B), US(O_FW1T), fb1, 128, 512, nullptr, US(O_FHB),
        nullptr, nullptr, nullptr, nullptr, nullptr, nullptr, nullptr, nullptr);
    // FFN2: xs1 + h2@fw2+fb2 -> LN2 -> t(bf16) + Poincare emb (f32 out + bf16) + e2/de
    k_gemm<EP_LN2HYP, 64><<<dim3(32, 1), 256, 0, stream>>>(
        US(O_FHB), US(O_FW2T), fb2, 512, 128, nullptr, US(O_TFB),
        g2, bt2, FP(O_XS1F), logc, out_emb, US(O_EMBB), FP(O_E2), FP(O_DE));
    // Heads: hyp (emb vs protos) + euc (t vs euc_w), fused
    k_heads<<<dim3(32, 158), 256, 0, stream>>>(
        US(O_EMBB), US(O_TFB), US(O_PROTB), US(O_EUCWT),
        FP(O_E2), FP(O_DE), FP(O_P2), FP(O_DP), euc_b, logc, out_hyp, out_euc);
}